// Round 1
// baseline (285.183 us; speedup 1.0000x reference)
//
#include <hip/hip_runtime.h>

#define NB 64
#define NT 48
#define NF 128
#define NE 64
#define NCD 32

// ---------------- kernel 1: m[b,f] = any_t mask[b,t,f] ----------------
__global__ __launch_bounds__(256) void mask_any_kernel(const int* __restrict__ mask,
                                                       float* __restrict__ mflag) {
    int idx = blockIdx.x * 256 + threadIdx.x;   // b*NF + f
    if (idx >= NB * NF) return;
    int b = idx >> 7;
    int f = idx & (NF - 1);
    const int* p = mask + b * (NT * NF) + f;
    int s = 0;
#pragma unroll
    for (int t = 0; t < NT; ++t) s += p[t * NF];
    mflag[idx] = (s != 0) ? 1.0f : 0.0f;
}

__device__ __forceinline__ void ld4(float* d, const float* p) {
    float4 v = *(const float4*)p;
    d[0] = v.x; d[1] = v.y; d[2] = v.z; d[3] = v.w;
}
__device__ __forceinline__ void st4(float* p, const float* s) {
    *(float4*)p = make_float4(s[0], s[1], s[2], s[3]);
}

// ---------------- kernel 2: fused per-(b,t) pipeline ----------------
// LDS plan (floats):
//   sCrm [128][68]  : c row-major (stride 68, 16B-aligned rows)     8704
//   sU   [16896]    : phase2a = CWt[64][132] @0 + Ct[64][132] @8448
//                     phase2b = P[128][132]
//                     phase2d = relu'd AGG[128][68]
//   sWt  [32][132]  : compress_w transposed                          4224
//   sx/sm/sbias[128]                                                  384
// total 30208 floats = 118 KiB -> 1 block/CU, 8 waves.
__global__ __launch_bounds__(512, 1) void fused_kernel(
    const float* __restrict__ input_x, const float* __restrict__ mflag,
    const float* __restrict__ embed0, const float* __restrict__ embed1,
    const float* __restrict__ embed_missing, const float* __restrict__ attn_w,
    const float* __restrict__ attn_b, const float* __restrict__ compress_w,
    float* __restrict__ out)
{
    __shared__ float sCrm[NF * 68];
    __shared__ float sU[16896];
    __shared__ float sWt[NCD * 132];
    __shared__ float sx[NF], sm[NF], sbias[NF];

    const int tid = threadIdx.x;
    const int bt = blockIdx.x;          // b*NT + t
    const int b = bt / NT;

    // ---- phase 0: small loads ----
    if (tid < 128) sx[tid] = input_x[bt * NF + tid];
    else if (tid < 256) sm[tid - 128] = mflag[b * NF + (tid - 128)];
    else if (tid < 384) sbias[tid - 256] = attn_b[tid - 256];
#pragma unroll
    for (int r = 0; r < 8; ++r) {
        int idx = tid + 512 * r;        // 4096 = 128*32
        int k = idx >> 5, d = idx & 31;
        sWt[d * 132 + k] = compress_w[idx];
    }
    __syncthreads();

    // ---- phase 1: c = x*e0 + (m-x)*e1 + (1-m)*emiss, three layouts ----
#pragma unroll
    for (int r = 0; r < 16; ++r) {
        int idx = tid + 512 * r;        // 8192 = 128*64, coalesced
        int f = idx >> 6, e = idx & 63;
        float x = sx[f], m = sm[f];
        float c = x * embed0[idx] + (m - x) * embed1[idx] + (1.0f - m) * embed_missing[idx];
        sCrm[f * 68 + e] = c;
        sU[e * 132 + f] = c * attn_w[idx];   // CWt[e][i]
        sU[8448 + e * 132 + f] = c;          // Ct[e][j]
    }
    __syncthreads();

    // ---- phase 2a: S = CW @ C^T, tile 8i x 4j per thread ----
    const int ti = tid >> 5, tj = tid & 31;
    const int i0 = ti * 8, j0 = tj * 4;
    float acc[8][4];
#pragma unroll
    for (int a = 0; a < 8; ++a)
#pragma unroll
        for (int q = 0; q < 4; ++q) acc[a][q] = 0.f;

#pragma unroll 4
    for (int e = 0; e < 64; ++e) {
        float cw[8], cj[4];
        ld4(cw, sU + e * 132 + i0);
        ld4(cw + 4, sU + e * 132 + i0 + 4);
        ld4(cj, sU + 8448 + e * 132 + j0);
#pragma unroll
        for (int a = 0; a < 8; ++a)
#pragma unroll
            for (int q = 0; q < 4; ++q) acc[a][q] += cw[a] * cj[q];
    }

    // ---- phase 2b: bias, clip, exp, zero-diag, row-normalize (in regs) ----
#pragma unroll
    for (int a = 0; a < 8; ++a) {
        const int irow = i0 + a;
        const float bias = sbias[irow];
        float rs = 0.f;
#pragma unroll
        for (int q = 0; q < 4; ++q) {
            float s = acc[a][q] + bias;
            s = fminf(fmaxf(s, -5.f), 5.f);
            float ev = __expf(s);
            if (irow == j0 + q) ev = 0.f;   // off-diagonal mask (after exp, like ref)
            acc[a][q] = ev;
            rs += ev;
        }
        // reduce across the 32 threads (tj) sharing this row block
#pragma unroll
        for (int msk = 1; msk < 32; msk <<= 1) rs += __shfl_xor(rs, msk);
        const float inv = 1.0f / (rs + 1e-8f);
#pragma unroll
        for (int q = 0; q < 4; ++q) acc[a][q] *= inv;
    }

    __syncthreads();                    // all CWt/Ct reads complete; safe to overwrite
#pragma unroll
    for (int a = 0; a < 8; ++a) st4(sU + (i0 + a) * 132 + j0, acc[a]);  // P[i][j]
    __syncthreads();

    // ---- phase 2c: AGG = (P @ C) .* C, relu; tile 4i x 4e per thread ----
    const int t_i = tid >> 4, t_e = tid & 15;
    const int ii0 = t_i * 4, e0 = t_e * 4;
    float ag[4][4];
#pragma unroll
    for (int q = 0; q < 4; ++q)
#pragma unroll
        for (int ee = 0; ee < 4; ++ee) ag[q][ee] = 0.f;

    for (int j = 0; j < 128; j += 4) {
        float pv[4][4], cv[4][4];
#pragma unroll
        for (int q = 0; q < 4; ++q) ld4(pv[q], sU + (ii0 + q) * 132 + j);
#pragma unroll
        for (int q = 0; q < 4; ++q) ld4(cv[q], sCrm + (j + q) * 68 + e0);
#pragma unroll
        for (int q = 0; q < 4; ++q)
#pragma unroll
            for (int jj = 0; jj < 4; ++jj)
#pragma unroll
                for (int ee = 0; ee < 4; ++ee)
                    ag[q][ee] += pv[q][jj] * cv[jj][ee];
    }
#pragma unroll
    for (int q = 0; q < 4; ++q) {
        float cv[4];
        ld4(cv, sCrm + (ii0 + q) * 68 + e0);
#pragma unroll
        for (int ee = 0; ee < 4; ++ee) {
            float v = ag[q][ee] * cv[ee];   // agg = c .* (P @ c)
            ag[q][ee] = v > 0.f ? v : 0.f;  // relu now; c-part relu'd on read later
        }
    }
    __syncthreads();                    // all P reads complete; safe to overwrite
#pragma unroll
    for (int q = 0; q < 4; ++q) st4(sU + (ii0 + q) * 68 + e0, ag[q]);   // AGG[f][e]
    __syncthreads();

    // ---- phase 3: OUT = relu([C, AGG]) @ Wc, tile 4f x 2d per thread ----
    const int t_f = tid >> 4, t_d = tid & 15;
    const int f0 = t_f * 4, d0 = t_d * 2;
    float o[4][2];
#pragma unroll
    for (int ff = 0; ff < 4; ++ff) { o[ff][0] = 0.f; o[ff][1] = 0.f; }

    for (int k = 0; k < 64; k += 4) {   // k in [0,64): C part (relu on read)
        float w0[4], w1[4];
        ld4(w0, sWt + (d0 + 0) * 132 + k);
        ld4(w1, sWt + (d0 + 1) * 132 + k);
#pragma unroll
        for (int ff = 0; ff < 4; ++ff) {
            float av[4];
            ld4(av, sCrm + (f0 + ff) * 68 + k);
#pragma unroll
            for (int q = 0; q < 4; ++q) {
                float a2 = fmaxf(av[q], 0.f);
                o[ff][0] += a2 * w0[q];
                o[ff][1] += a2 * w1[q];
            }
        }
    }
    for (int k = 0; k < 64; k += 4) {   // k in [64,128): AGG part (already relu'd)
        float w0[4], w1[4];
        ld4(w0, sWt + (d0 + 0) * 132 + 64 + k);
        ld4(w1, sWt + (d0 + 1) * 132 + 64 + k);
#pragma unroll
        for (int ff = 0; ff < 4; ++ff) {
            float av[4];
            ld4(av, sU + (f0 + ff) * 68 + k);
#pragma unroll
            for (int q = 0; q < 4; ++q) {
                o[ff][0] += av[q] * w0[q];
                o[ff][1] += av[q] * w1[q];
            }
        }
    }

    float* op = out + (bt * NF + f0) * NCD + d0;
#pragma unroll
    for (int ff = 0; ff < 4; ++ff)
        *(float2*)(op + ff * NCD) = make_float2(o[ff][0], o[ff][1]);
}

extern "C" void kernel_launch(void* const* d_in, const int* in_sizes, int n_in,
                              void* d_out, int out_size, void* d_ws, size_t ws_size,
                              hipStream_t stream) {
    const float* input_x       = (const float*)d_in[0];
    const int*   mask          = (const int*)d_in[1];
    const float* embed0        = (const float*)d_in[2];
    const float* embed1        = (const float*)d_in[3];
    const float* embed_missing = (const float*)d_in[4];
    const float* attn_w        = (const float*)d_in[5];
    const float* attn_b        = (const float*)d_in[6];
    const float* compress_w    = (const float*)d_in[7];
    float* out   = (float*)d_out;
    float* mflag = (float*)d_ws;   // NB*NF floats = 32 KiB

    hipLaunchKernelGGL(mask_any_kernel, dim3((NB * NF + 255) / 256), dim3(256), 0, stream,
                       mask, mflag);
    hipLaunchKernelGGL(fused_kernel, dim3(NB * NT), dim3(512), 0, stream,
                       input_x, mflag, embed0, embed1, embed_missing,
                       attn_w, attn_b, compress_w, out);
}

// Round 2
// 69.567 us; speedup vs baseline: 4.0994x; 4.0994x over previous
//
#include <hip/hip_runtime.h>

#define NB 64
#define NT 48
#define NF 128
#define NE 64
#define NCD 32

#define CB_S 72    // bf16 stride for [f][e]-type tiles (144 B rows, 16B-aligned, 2-way max)
#define PT_S 136   // bf16 stride for [.][128]-type tiles (272 B rows, 16B-aligned, 2-way max)

typedef __attribute__((ext_vector_type(8))) short bf16x8;
typedef __attribute__((ext_vector_type(4))) float f32x4;

__device__ __forceinline__ ushort f2bf(float x) {
    union { float f; uint u; } v; v.f = x;
    uint r = v.u + 0x7fffu + ((v.u >> 16) & 1u);   // RNE
    return (ushort)(r >> 16);
}
__device__ __forceinline__ float bf2f(ushort u) {
    union { uint u; float f; } v; v.u = ((uint)u) << 16;
    return v.f;
}

// ---------------- kernel 1: m[b,f] = any_t mask[b,t,f] ----------------
__global__ __launch_bounds__(256) void mask_any_kernel(const int* __restrict__ mask,
                                                       float* __restrict__ mflag) {
    int idx = blockIdx.x * 256 + threadIdx.x;   // b*NF + f
    if (idx >= NB * NF) return;
    int b = idx >> 7;
    int f = idx & (NF - 1);
    const int* p = mask + b * (NT * NF) + f;
    int s = 0;
#pragma unroll
    for (int t = 0; t < NT; ++t) s += p[t * NF];
    mflag[idx] = (s != 0) ? 1.0f : 0.0f;
}

// ---------------- kernel 2: fused per-(b,t) MFMA pipeline ----------------
// LDS (bf16/ushort):
//   sCb [128][72]  c row-major                          18432 B
//   sU  [128][136] phase S: CWb[128][72]; then P[128][136]   34816 B
//   sV  [9216]     phase S/AGG: Ct[64][136]; then A2[128][72] 18432 B
//   sWt [32][136]  compress_w^T                          8704 B
//   sbias[128] f32                                        512 B
// total 80896 B -> 2 blocks/CU (161792 <= 163840), 16 waves/CU.
__global__ __launch_bounds__(512, 4) void fused_kernel(
    const float* __restrict__ input_x, const float* __restrict__ mflag,
    const float* __restrict__ embed0, const float* __restrict__ embed1,
    const float* __restrict__ embed_missing, const float* __restrict__ attn_w,
    const float* __restrict__ attn_b, const float* __restrict__ compress_w,
    float* __restrict__ out)
{
    __shared__ ushort sCb[NF * CB_S];
    __shared__ ushort sU[NF * PT_S];
    __shared__ ushort sV[NF * CB_S];
    __shared__ ushort sWt[NCD * PT_S];
    __shared__ float sbias[NF];

    const int tid = threadIdx.x;
    const int bt = blockIdx.x;          // b*NT + t
    const int b = bt / NT;

    // ---- phase 1: embeddings -> c (three bf16 layouts) + Wt + bias ----
    if (tid < NF) sbias[tid] = attn_b[tid];
    {
        const int k = tid >> 2;
        const int d0 = (tid & 3) << 3;
        const float* wp = compress_w + k * NCD + d0;
#pragma unroll
        for (int q = 0; q < 8; ++q) sWt[(d0 + q) * PT_S + k] = f2bf(wp[q]);
    }
    {
        const int f = tid >> 2;
        const int eb = (tid & 3) << 4;
        const float x = input_x[bt * NF + f];
        const float m = mflag[b * NF + f];
        const float mmx = m - x, om = 1.0f - m;
        const int base = f * NE + eb;
        bf16x8 cb0, cb1, cw0, cw1;
#pragma unroll
        for (int j = 0; j < 16; j += 4) {
            float4 e0v = *(const float4*)(embed0 + base + j);
            float4 e1v = *(const float4*)(embed1 + base + j);
            float4 emv = *(const float4*)(embed_missing + base + j);
            float4 awv = *(const float4*)(attn_w + base + j);
            float cc[4], ww[4];
            cc[0] = x * e0v.x + mmx * e1v.x + om * emv.x; ww[0] = awv.x;
            cc[1] = x * e0v.y + mmx * e1v.y + om * emv.y; ww[1] = awv.y;
            cc[2] = x * e0v.z + mmx * e1v.z + om * emv.z; ww[2] = awv.z;
            cc[3] = x * e0v.w + mmx * e1v.w + om * emv.w; ww[3] = awv.w;
#pragma unroll
            for (int q = 0; q < 4; ++q) {
                const int e = j + q;
                ushort cbv = f2bf(cc[q]);
                ushort cwv = f2bf(cc[q] * ww[q]);
                if (e < 8) { cb0[e] = (short)cbv; cw0[e] = (short)cwv; }
                else       { cb1[e - 8] = (short)cbv; cw1[e - 8] = (short)cwv; }
                sV[(eb + e) * PT_S + f] = cbv;   // Ct[e][f]
            }
        }
        *(bf16x8*)&sCb[f * CB_S + eb] = cb0;
        *(bf16x8*)&sCb[f * CB_S + eb + 8] = cb1;
        *(bf16x8*)&sU[f * CB_S + eb] = cw0;      // CWb[f][e]
        *(bf16x8*)&sU[f * CB_S + eb + 8] = cw1;
    }
    __syncthreads();

    const int wv = tid >> 6, ln = tid & 63;
    const int lr = ln & 15, lg = ln >> 4;
    const int i0 = wv << 4;                      // this wave's 16-row strip
    const int ib = i0 + (lg << 2);               // D-layout row base for this lane

    // ---- phase S: S = CW @ C^T (8 col-tiles, K=64) ----
    f32x4 acc[8];
#pragma unroll
    for (int t = 0; t < 8; ++t) acc[t] = (f32x4){0.f, 0.f, 0.f, 0.f};
#pragma unroll
    for (int ks = 0; ks < 2; ++ks) {
        bf16x8 afr = *(bf16x8*)&sU[(i0 + lr) * CB_S + ks * 32 + lg * 8];
#pragma unroll
        for (int t = 0; t < 8; ++t) {
            bf16x8 bfr = *(bf16x8*)&sCb[((t << 4) + lr) * CB_S + ks * 32 + lg * 8];
            acc[t] = __builtin_amdgcn_mfma_f32_16x16x32_bf16(afr, bfr, acc[t], 0, 0, 0);
        }
    }

    // ---- softmax in registers (row = 16 lanes with same lg) ----
    float inv[4];
    {
        float rs[4] = {0.f, 0.f, 0.f, 0.f};
#pragma unroll
        for (int t = 0; t < 8; ++t) {
#pragma unroll
            for (int r = 0; r < 4; ++r) {
                float s = acc[t][r] + sbias[ib + r];
                s = fminf(fmaxf(s, -5.f), 5.f);
                float e = __expf(s);
                if (((t << 4) + lr) == (ib + r)) e = 0.f;   // zero diagonal
                acc[t][r] = e;
                rs[r] += e;
            }
        }
#pragma unroll
        for (int r = 0; r < 4; ++r) {
            rs[r] += __shfl_xor(rs[r], 1);
            rs[r] += __shfl_xor(rs[r], 2);
            rs[r] += __shfl_xor(rs[r], 4);
            rs[r] += __shfl_xor(rs[r], 8);
            inv[r] = 1.0f / (rs[r] + 1e-8f);
        }
    }

    __syncthreads();   // all CWb reads complete -> sU becomes P
#pragma unroll
    for (int t = 0; t < 8; ++t)
#pragma unroll
        for (int r = 0; r < 4; ++r)
            sU[(ib + r) * PT_S + (t << 4) + lr] = f2bf(acc[t][r] * inv[r]);
    __syncthreads();   // P visible (also guards cross-lane write->read)

    // ---- phase AGG: (P @ C) for own strip, then .*C + relu ----
    f32x4 agc[4];
#pragma unroll
    for (int et = 0; et < 4; ++et) agc[et] = (f32x4){0.f, 0.f, 0.f, 0.f};
#pragma unroll
    for (int ks = 0; ks < 4; ++ks) {
        bf16x8 afr = *(bf16x8*)&sU[(i0 + lr) * PT_S + ks * 32 + lg * 8];
#pragma unroll
        for (int et = 0; et < 4; ++et) {
            bf16x8 bfr = *(bf16x8*)&sV[((et << 4) + lr) * PT_S + ks * 32 + lg * 8];
            agc[et] = __builtin_amdgcn_mfma_f32_16x16x32_bf16(afr, bfr, agc[et], 0, 0, 0);
        }
    }
    float av[4][4];
#pragma unroll
    for (int et = 0; et < 4; ++et)
#pragma unroll
        for (int r = 0; r < 4; ++r) {
            float cv = bf2f(sCb[(ib + r) * CB_S + (et << 4) + lr]);
            float v = agc[et][r] * cv;
            av[et][r] = v > 0.f ? v : 0.f;
        }
    __syncthreads();   // all Ct reads complete -> sV becomes A2
#pragma unroll
    for (int et = 0; et < 4; ++et)
#pragma unroll
        for (int r = 0; r < 4; ++r)
            sV[(ib + r) * CB_S + (et << 4) + lr] = f2bf(av[et][r]);
    __syncthreads();   // A2 visible

    // ---- phase OUT: relu([C,A2]) @ Wc ----
    f32x4 oc[2];
    oc[0] = (f32x4){0.f, 0.f, 0.f, 0.f};
    oc[1] = (f32x4){0.f, 0.f, 0.f, 0.f};
#pragma unroll
    for (int ks = 0; ks < 4; ++ks) {
        bf16x8 afr;
        if (ks < 2) {
            afr = *(bf16x8*)&sCb[(i0 + lr) * CB_S + ks * 32 + lg * 8];
#pragma unroll
            for (int q = 0; q < 8; ++q) afr[q] = afr[q] < (short)0 ? (short)0 : afr[q];  // bf16 relu via int16 sign
        } else {
            afr = *(bf16x8*)&sV[(i0 + lr) * CB_S + (ks - 2) * 32 + lg * 8];
        }
#pragma unroll
        for (int dt = 0; dt < 2; ++dt) {
            bf16x8 bfr = *(bf16x8*)&sWt[((dt << 4) + lr) * PT_S + ks * 32 + lg * 8];
            oc[dt] = __builtin_amdgcn_mfma_f32_16x16x32_bf16(afr, bfr, oc[dt], 0, 0, 0);
        }
    }
    float* op = out + bt * (NF * NCD);
#pragma unroll
    for (int dt = 0; dt < 2; ++dt)
#pragma unroll
        for (int r = 0; r < 4; ++r)
            op[(ib + r) * NCD + (dt << 4) + lr] = oc[dt][r];
}

extern "C" void kernel_launch(void* const* d_in, const int* in_sizes, int n_in,
                              void* d_out, int out_size, void* d_ws, size_t ws_size,
                              hipStream_t stream) {
    const float* input_x       = (const float*)d_in[0];
    const int*   mask          = (const int*)d_in[1];
    const float* embed0        = (const float*)d_in[2];
    const float* embed1       = (const float*)d_in[3];
    const float* embed_missing = (const float*)d_in[4];
    const float* attn_w        = (const float*)d_in[5];
    const float* attn_b        = (const float*)d_in[6];
    const float* compress_w    = (const float*)d_in[7];
    float* out   = (float*)d_out;
    float* mflag = (float*)d_ws;   // NB*NF floats = 32 KiB

    hipLaunchKernelGGL(mask_any_kernel, dim3((NB * NF + 255) / 256), dim3(256), 0, stream,
                       mask, mflag);
    hipLaunchKernelGGL(fused_kernel, dim3(NB * NT), dim3(512), 0, stream,
                       input_x, mflag, embed0, embed1, embed_missing,
                       attn_w, attn_b, compress_w, out);
}

// Round 3
// 56.199 us; speedup vs baseline: 5.0745x; 1.2379x over previous
//
#include <hip/hip_runtime.h>

#define NB 64
#define NT 48
#define NF 128
#define NE 64
#define NCD 32

#define CB_S 72    // u16 stride for [128][64]-type tiles (144 B rows)
#define PT_S 136   // u16 stride for [.][128]-type tiles (272 B rows)

typedef __attribute__((ext_vector_type(8))) short bf16x8;
typedef __attribute__((ext_vector_type(4))) float f32x4;

// ---- ws layout (bytes) ----
#define WS_MFLAG 0        // 8192 f32 = 32768 B
#define WS_E0    32768    // 8192 u16
#define WS_E1    49152
#define WS_EM    65536
#define WS_WT    81920    // [32][136] u16 = 8704 B  (pad cols never consumed)

__device__ __forceinline__ ushort f2bf(float x) {
    union { float f; uint u; } v; v.f = x;
    uint r = v.u + 0x7fffu + ((v.u >> 16) & 1u);   // RNE
    return (ushort)(r >> 16);
}
__device__ __forceinline__ uint pk_bf16(float lo, float hi) {   // v_cvt_pk_bf16_f32 (RNE)
    uint r; asm("v_cvt_pk_bf16_f32 %0, %1, %2" : "=v"(r) : "v"(lo), "v"(hi)); return r;
}
__device__ __forceinline__ float bflo(uint u) { union { uint u; float f; } v; v.u = u << 16; return v.f; }
__device__ __forceinline__ float bfhi(uint u) { union { uint u; float f; } v; v.u = u & 0xffff0000u; return v.f; }
__device__ __forceinline__ float bf2f(ushort u) { union { uint u; float f; } v; v.u = ((uint)u) << 16; return v.f; }

// ---------------- kernel 1: prep (mask-any + bf16 conversions + Wt transpose) ----------------
__global__ __launch_bounds__(256) void prep_kernel(
    const int* __restrict__ mask, const float* __restrict__ e0, const float* __restrict__ e1,
    const float* __restrict__ em, const float* __restrict__ cw,
    float* __restrict__ mflag, ushort* __restrict__ e0b, ushort* __restrict__ e1b,
    ushort* __restrict__ emb, ushort* __restrict__ wt)
{
    const int blk = blockIdx.x, tid = threadIdx.x;
    if (blk < 32) {                     // embed tables -> bf16
        int idx = blk * 256 + tid;      // 8192
        e0b[idx] = f2bf(e0[idx]);
        e1b[idx] = f2bf(e1[idx]);
        emb[idx] = f2bf(em[idx]);
    } else if (blk < 64) {              // m[b,f] = any_t mask
        int idx = (blk - 32) * 256 + tid;
        int b = idx >> 7, f = idx & 127;
        const int* p = mask + b * (NT * NF) + f;
        int s = 0;
#pragma unroll
        for (int t = 0; t < NT; ++t) s += p[t * NF];
        mflag[idx] = (s != 0) ? 1.0f : 0.0f;
    } else {                            // compress_w [128][32] -> Wt bf16 [32][136]
        int idx = (blk - 64) * 256 + tid;
        if (idx < 4096) { int k = idx >> 5, d = idx & 31; wt[d * PT_S + k] = f2bf(cw[idx]); }
    }
}

// ---------------- kernel 2: fused per-(b,t) MFMA pipeline, 2 barriers ----------------
// LDS (u16): sCb[128][72] 18432B | sP[128][136] 34816B | sV max(Ct 64x136, A2 128x72) 18432B
//            sWt[32][136] 8704B  -> total 80384B -> 2 blocks/CU.
__global__ __launch_bounds__(512, 4) void fused_kernel(
    const float* __restrict__ input_x, const float* __restrict__ mflag,
    const ushort* __restrict__ e0b, const ushort* __restrict__ e1b, const ushort* __restrict__ emb,
    const float* __restrict__ attn_w, const float* __restrict__ attn_b,
    const ushort* __restrict__ wt, float* __restrict__ out)
{
    __shared__ ushort sCb[NF * CB_S];
    __shared__ ushort sP[NF * PT_S];
    __shared__ ushort sV[NF * CB_S];    // Ct (phase S/AGG), then A2
    __shared__ ushort sWt[NCD * PT_S];

    const int tid = threadIdx.x;
    const int bt = blockIdx.x;          // b*NT + t
    const int b = bt / NT;

    const int wv = tid >> 6, ln = tid & 63;
    const int lr = ln & 15, lg = ln >> 4;
    const int i0 = wv << 4;             // this wave's 16-row strip
    const int ib = i0 + (lg << 2);      // C/D-layout row base for this lane

    // ---- hoisted global loads (latency hidden under phase 1) ----
    float wA[2][8];
#pragma unroll
    for (int ks = 0; ks < 2; ++ks) {
        const float* wp = attn_w + (i0 + lr) * NE + ks * 32 + lg * 8;
        *(float4*)&wA[ks][0] = *(const float4*)wp;
        *(float4*)&wA[ks][4] = *(const float4*)(wp + 4);
    }
    const float4 b4 = *(const float4*)(attn_b + ib);
    const float bias_[4] = {b4.x, b4.y, b4.z, b4.w};

    // ---- phase 1: Wt copy + c in two bf16 layouts ----
    {
        const uint* wsrc = (const uint*)wt;
        uint* wdst = (uint*)sWt;
#pragma unroll
        for (int i = 0; i < 4; ++i) wdst[tid + 512 * i] = wsrc[tid + 512 * i];
        if (tid < 128) wdst[2048 + tid] = wsrc[2048 + tid];
    }
    {
        const int f = tid >> 2, g = tid & 3, eb = g << 4;
        const float x = input_x[bt * NF + f];
        const float m = mflag[b * NF + f];
        const float mmx = m - x, om = 1.0f - m;
        const uint* p0 = (const uint*)(e0b + f * NE + eb);   // 8 dwords = 16 bf16
        const uint* p1 = (const uint*)(e1b + f * NE + eb);
        const uint* p2 = (const uint*)(emb + f * NE + eb);
        float c[16];
#pragma unroll
        for (int j = 0; j < 8; ++j) {
            uint u0 = p0[j], u1 = p1[j], u2 = p2[j];
            c[2 * j]     = x * bflo(u0) + mmx * bflo(u1) + om * bflo(u2);
            c[2 * j + 1] = x * bfhi(u0) + mmx * bfhi(u1) + om * bfhi(u2);
        }
        uint cb[8];
#pragma unroll
        for (int j = 0; j < 8; ++j) cb[j] = pk_bf16(c[2 * j], c[2 * j + 1]);
        *(uint4*)&sCb[f * CB_S + eb] = make_uint4(cb[0], cb[1], cb[2], cb[3]);
        *(uint4*)&sCb[f * CB_S + eb + 8] = make_uint4(cb[4], cb[5], cb[6], cb[7]);
        // Ct[e][f] with column-block XOR swizzle: blk' = (f>>3) ^ (g<<1)  (write conflict-free)
        const int col = (((f >> 3) ^ (g << 1)) << 3) | (f & 7);
#pragma unroll
        for (int j = 0; j < 8; ++j) {
            sV[(eb + 2 * j) * PT_S + col]     = (ushort)cb[j];
            sV[(eb + 2 * j + 1) * PT_S + col] = (ushort)(cb[j] >> 16);
        }
    }
    __syncthreads();                    // barrier 1: Cb/Ct/Wt visible

    // ---- phase S: S = (C.*W) @ C^T  (A built in regs from C-frag x W-frag) ----
    f32x4 acc[8];
#pragma unroll
    for (int t = 0; t < 8; ++t) acc[t] = (f32x4){0.f, 0.f, 0.f, 0.f};
#pragma unroll
    for (int ks = 0; ks < 2; ++ks) {
        bf16x8 cf = *(bf16x8*)&sCb[(i0 + lr) * CB_S + ks * 32 + lg * 8];
        const uint* cu = (const uint*)&cf;
        union { uint u[4]; bf16x8 v; } afr;
#pragma unroll
        for (int j = 0; j < 4; ++j)
            afr.u[j] = pk_bf16(bflo(cu[j]) * wA[ks][2 * j], bfhi(cu[j]) * wA[ks][2 * j + 1]);
#pragma unroll
        for (int t = 0; t < 8; ++t) {
            bf16x8 bfr = *(bf16x8*)&sCb[((t << 4) + lr) * CB_S + ks * 32 + lg * 8];
            acc[t] = __builtin_amdgcn_mfma_f32_16x16x32_bf16(afr.v, bfr, acc[t], 0, 0, 0);
        }
    }

    // ---- softmax in registers (row = 16 lanes sharing lg) ----
    float inv[4];
    {
        float rs[4] = {0.f, 0.f, 0.f, 0.f};
#pragma unroll
        for (int t = 0; t < 8; ++t) {
#pragma unroll
            for (int r = 0; r < 4; ++r) {
                float s = acc[t][r] + bias_[r];
                s = fminf(fmaxf(s, -5.f), 5.f);
                float e = __expf(s);
                if (((t << 4) + lr) == (ib + r)) e = 0.f;   // zero diagonal
                acc[t][r] = e;
                rs[r] += e;
            }
        }
#pragma unroll
        for (int r = 0; r < 4; ++r) {
            rs[r] += __shfl_xor(rs[r], 1);
            rs[r] += __shfl_xor(rs[r], 2);
            rs[r] += __shfl_xor(rs[r], 4);
            rs[r] += __shfl_xor(rs[r], 8);
            inv[r] = 1.0f / (rs[r] + 1e-8f);
        }
    }

    // ---- P store (dedicated buffer, wave-local -> no barrier) ----
#pragma unroll
    for (int r = 0; r < 4; ++r) {
        const int rowo = (ib + r) * PT_S + lr;
#pragma unroll
        for (int t = 0; t < 8; t += 2) {
            uint pr = pk_bf16(acc[t][r] * inv[r], acc[t + 1][r] * inv[r]);
            sP[rowo + (t << 4)] = (ushort)pr;
            sP[rowo + ((t + 1) << 4)] = (ushort)(pr >> 16);
        }
    }

    // ---- phase AGG: (P @ C) for own strip ----
    f32x4 agc[4];
#pragma unroll
    for (int et = 0; et < 4; ++et) agc[et] = (f32x4){0.f, 0.f, 0.f, 0.f};
#pragma unroll
    for (int ks = 0; ks < 4; ++ks) {
        bf16x8 afr = *(bf16x8*)&sP[(i0 + lr) * PT_S + ks * 32 + lg * 8];
#pragma unroll
        for (int et = 0; et < 4; ++et) {
            bf16x8 bfr = *(bf16x8*)&sV[((et << 4) + lr) * PT_S + (((((ks << 2) | lg)) ^ (et << 1)) << 3)];
            agc[et] = __builtin_amdgcn_mfma_f32_16x16x32_bf16(afr, bfr, agc[et], 0, 0, 0);
        }
    }
    // epilogue: .*C + relu (in regs)
    float av[4][4];
#pragma unroll
    for (int et = 0; et < 4; ++et)
#pragma unroll
        for (int r = 0; r < 4; ++r) {
            float cv = bf2f(sCb[(ib + r) * CB_S + (et << 4) + lr]);
            av[et][r] = fmaxf(agc[et][r] * cv, 0.f);
        }
    __syncthreads();                    // barrier 2: all Ct reads done -> sV becomes A2

    // ---- A2 store (wave-local rows) ----
#pragma unroll
    for (int et = 0; et < 4; ++et) {
        const int colo = (et << 4) + lr;
#pragma unroll
        for (int r = 0; r < 4; r += 2) {
            uint pr = pk_bf16(av[et][r], av[et][r + 1]);
            sV[(ib + r) * CB_S + colo] = (ushort)pr;
            sV[(ib + r + 1) * CB_S + colo] = (ushort)(pr >> 16);
        }
    }

    // ---- phase OUT: relu([C, A2]) @ Wc ----
    f32x4 oc[2];
    oc[0] = (f32x4){0.f, 0.f, 0.f, 0.f};
    oc[1] = (f32x4){0.f, 0.f, 0.f, 0.f};
#pragma unroll
    for (int ks = 0; ks < 4; ++ks) {
        bf16x8 afr;
        if (ks < 2) {
            afr = *(bf16x8*)&sCb[(i0 + lr) * CB_S + ks * 32 + lg * 8];
#pragma unroll
            for (int q = 0; q < 8; ++q) afr[q] = afr[q] < (short)0 ? (short)0 : afr[q];  // bf16 relu (i16 max)
        } else {
            afr = *(bf16x8*)&sV[(i0 + lr) * CB_S + (ks - 2) * 32 + lg * 8];
        }
#pragma unroll
        for (int dt = 0; dt < 2; ++dt) {
            bf16x8 bfr = *(bf16x8*)&sWt[((dt << 4) + lr) * PT_S + ks * 32 + lg * 8];
            oc[dt] = __builtin_amdgcn_mfma_f32_16x16x32_bf16(afr, bfr, oc[dt], 0, 0, 0);
        }
    }
    float* op = out + bt * (NF * NCD);
#pragma unroll
    for (int dt = 0; dt < 2; ++dt)
#pragma unroll
        for (int r = 0; r < 4; ++r)
            op[(ib + r) * NCD + (dt << 4) + lr] = oc[dt][r];
}

extern "C" void kernel_launch(void* const* d_in, const int* in_sizes, int n_in,
                              void* d_out, int out_size, void* d_ws, size_t ws_size,
                              hipStream_t stream) {
    const float* input_x       = (const float*)d_in[0];
    const int*   mask          = (const int*)d_in[1];
    const float* embed0        = (const float*)d_in[2];
    const float* embed1        = (const float*)d_in[3];
    const float* embed_missing = (const float*)d_in[4];
    const float* attn_w        = (const float*)d_in[5];
    const float* attn_b        = (const float*)d_in[6];
    const float* compress_w    = (const float*)d_in[7];
    float* out = (float*)d_out;

    char* ws = (char*)d_ws;
    float*  mflag = (float*)(ws + WS_MFLAG);
    ushort* e0b   = (ushort*)(ws + WS_E0);
    ushort* e1b   = (ushort*)(ws + WS_E1);
    ushort* emb   = (ushort*)(ws + WS_EM);
    ushort* wt    = (ushort*)(ws + WS_WT);

    hipLaunchKernelGGL(prep_kernel, dim3(80), dim3(256), 0, stream,
                       mask, embed0, embed1, embed_missing, compress_w,
                       mflag, e0b, e1b, emb, wt);
    hipLaunchKernelGGL(fused_kernel, dim3(NB * NT), dim3(512), 0, stream,
                       input_x, mflag, e0b, e1b, emb, attn_w, attn_b, wt, out);
}

// Round 4
// 50.397 us; speedup vs baseline: 5.6588x; 1.1151x over previous
//
#include <hip/hip_runtime.h>

#define NB 64
#define NT 48
#define NF 128
#define NE 64
#define NCD 32

#define CB_S 72    // sCb stride (u16): 144B rows, b128-aligned, conflict-free reads
#define CT_S 136   // Ct stride (u16): 272B rows, 68 dwords == 4 mod 32
#define A2_S 72    // A2 stride (u16), overlays sV
#define PS_S 40    // per-wave P chunk stride (u16): 80B rows, 16B-aligned at 8*lg

typedef __attribute__((ext_vector_type(8))) short bf16x8;
typedef __attribute__((ext_vector_type(4))) float f32x4;

// ---- ws layout (bytes) ----
#define WS_MFLAG 0        // 8192 u32
#define WS_DB    32768    // 8192 u16 each
#define WS_E1B   49152
#define WS_EMB   65536
#define WS_WB    81920
#define WS_WT    98304    // [32][128] u16 = 8192 B
// total 106496 B

__device__ __forceinline__ ushort f2bf(float x) {
    union { float f; uint u; } v; v.f = x;
    uint r = v.u + 0x7fffu + ((v.u >> 16) & 1u);   // RNE
    return (ushort)(r >> 16);
}
__device__ __forceinline__ uint pk_bf16(float lo, float hi) {   // v_cvt_pk_bf16_f32
    uint r; asm("v_cvt_pk_bf16_f32 %0, %1, %2" : "=v"(r) : "v"(lo), "v"(hi)); return r;
}
__device__ __forceinline__ float bflo(uint u) { union { uint u; float f; } v; v.u = u << 16; return v.f; }
__device__ __forceinline__ float bfhi(uint u) { union { uint u; float f; } v; v.u = u & 0xffff0000u; return v.f; }

// ---------------- kernel 1: prep ----------------
__global__ __launch_bounds__(256) void prep_kernel(
    const int* __restrict__ mask, const float* __restrict__ e0, const float* __restrict__ e1,
    const float* __restrict__ em, const float* __restrict__ aw, const float* __restrict__ cw,
    uint* __restrict__ mflag, ushort* __restrict__ db, ushort* __restrict__ e1b,
    ushort* __restrict__ emb, ushort* __restrict__ wb, ushort* __restrict__ wt)
{
    const int blk = blockIdx.x, tid = threadIdx.x;
    if (blk < 32) {                     // tables -> bf16 (+ D = e0-e1)
        int idx = blk * 256 + tid;      // 8192
        float e1v = e1[idx], emv = em[idx];
        e1b[idx] = f2bf(e1v);
        emb[idx] = f2bf(emv);
        db[idx]  = f2bf(e0[idx] - e1v);
        wb[idx]  = f2bf(aw[idx]);
    } else if (blk < 64) {              // m[b,f] = any_t mask
        int idx = (blk - 32) * 256 + tid;
        int b = idx >> 7, f = idx & 127;
        const int* p = mask + b * (NT * NF) + f;
        int s = 0;
#pragma unroll
        for (int t = 0; t < NT; ++t) s += p[t * NF];
        mflag[idx] = (s != 0) ? 1u : 0u;
    } else {                            // compress_w [128][32] -> wt bf16 [32][128]
        int idx = (blk - 64) * 256 + tid;
        if (idx < 4096) { int k = idx >> 5, d = idx & 31; wt[d * 128 + k] = f2bf(cw[idx]); }
    }
}

// ---------------- kernel 2: fused per-(b,t) MFMA pipeline ----------------
// LDS: sCb[128][72] 18432B | sV 18432B (Ct[64][136]=17408B, then A2[128][72]) |
//      sPs 8 waves x [16][40] 10240B  -> total 47104B -> 3 blocks/CU, 24 waves/CU.
__global__ __launch_bounds__(512, 6) void fused_kernel(
    const float* __restrict__ input_x, const uint* __restrict__ mflag,
    const ushort* __restrict__ db, const ushort* __restrict__ e1b, const ushort* __restrict__ emb,
    const ushort* __restrict__ wb, const float* __restrict__ attn_b,
    const ushort* __restrict__ wt, float* __restrict__ out)
{
    __shared__ ushort sCb[NF * CB_S];       // 9216 u16
    __shared__ ushort sV[NF * A2_S];        // 9216 u16 (Ct then A2)
    __shared__ ushort sPs[8 * 16 * PS_S];   // 5120 u16

    const int tid = threadIdx.x;
    const int bt = blockIdx.x;          // b*NT + t
    const int b = bt / NT;

    const int wv = tid >> 6, ln = tid & 63;
    const int lr = ln & 15, lg = ln >> 4;
    const int i0 = wv << 4, irow = i0 + lr;

    // ---- hoisted globals (latency hidden under phase 1) ----
    const float bias = attn_b[irow];
    const uint4 wk0 = *(const uint4*)(wb + irow * NE + lg * 8);
    const uint4 wk1 = *(const uint4*)(wb + irow * NE + 32 + lg * 8);

    // ---- phase 1: c = x*D + (m ? e1 : em), two bf16 layouts ----
    {
        const int f = tid >> 2, g = tid & 3, eb = g << 4;
        const float x = input_x[bt * NF + f];
        const ushort* Mrow = (mflag[b * NF + f] ? e1b : emb) + f * NE + eb;
        const ushort* Drow = db + f * NE + eb;
        uint dd[8], mm[8];
        *(uint4*)&dd[0] = *(const uint4*)Drow;
        *(uint4*)&dd[4] = *(const uint4*)(Drow + 8);
        *(uint4*)&mm[0] = *(const uint4*)Mrow;
        *(uint4*)&mm[4] = *(const uint4*)(Mrow + 8);
        uint cb[8];
#pragma unroll
        for (int j = 0; j < 8; ++j) {
            float clo = fmaf(x, bflo(dd[j]), bflo(mm[j]));
            float chi = fmaf(x, bfhi(dd[j]), bfhi(mm[j]));
            cb[j] = pk_bf16(clo, chi);
        }
        *(uint4*)&sCb[f * CB_S + eb]     = *(uint4*)&cb[0];
        *(uint4*)&sCb[f * CB_S + eb + 8] = *(uint4*)&cb[4];
        // Ct[e][f], column-block XOR swizzle (write conflict-free)
        const int col = ((((f >> 3) ^ (g << 1)) << 3) | (f & 7));
#pragma unroll
        for (int j = 0; j < 8; ++j) {
            sV[(eb + 2 * j) * CT_S + col]     = (ushort)cb[j];
            sV[(eb + 2 * j + 1) * CT_S + col] = (ushort)(cb[j] >> 16);
        }
    }
    __syncthreads();                    // barrier 1: Cb/Ct visible

    // ---- B-frag build: CW[irow][e-slice] = C * W in regs ----
    bf16x8 cwf[2];
    {
        bf16x8 cf0 = *(bf16x8*)&sCb[irow * CB_S + lg * 8];
        bf16x8 cf1 = *(bf16x8*)&sCb[irow * CB_S + 32 + lg * 8];
        const uint* cu0 = (const uint*)&cf0; const uint* wu0 = (const uint*)&wk0;
        const uint* cu1 = (const uint*)&cf1; const uint* wu1 = (const uint*)&wk1;
        union { uint u[4]; bf16x8 v; } a0, a1;
#pragma unroll
        for (int j = 0; j < 4; ++j) {
            a0.u[j] = pk_bf16(bflo(cu0[j]) * bflo(wu0[j]), bfhi(cu0[j]) * bfhi(wu0[j]));
            a1.u[j] = pk_bf16(bflo(cu1[j]) * bflo(wu1[j]), bfhi(cu1[j]) * bfhi(wu1[j]));
        }
        cwf[0] = a0.v; cwf[1] = a1.v;
    }

    // ---- phase S: S^T tiles -> lane holds S[irow][16jt+4lg+r] ----
    f32x4 st[8];
#pragma unroll
    for (int jt = 0; jt < 8; ++jt) {
        f32x4 a = (f32x4){0.f, 0.f, 0.f, 0.f};
        bf16x8 f0 = *(bf16x8*)&sCb[((jt << 4) + lr) * CB_S + lg * 8];
        a = __builtin_amdgcn_mfma_f32_16x16x32_bf16(f0, cwf[0], a, 0, 0, 0);
        bf16x8 f1 = *(bf16x8*)&sCb[((jt << 4) + lr) * CB_S + 32 + lg * 8];
        a = __builtin_amdgcn_mfma_f32_16x16x32_bf16(f1, cwf[1], a, 0, 0, 0);
        st[jt] = a;
    }

    // ---- softmax numerator (row lane-local; normalization deferred) ----
    float rs = 0.f;
#pragma unroll
    for (int jt = 0; jt < 8; ++jt) {
#pragma unroll
        for (int r = 0; r < 4; ++r) {
            float s = st[jt][r] + bias;
            s = fminf(fmaxf(s, -5.f), 5.f);
            float e = __expf(s);
            const int col = (jt << 4) + (lg << 2) + r;
            e = (col == irow) ? 0.f : e;   // zero diagonal
            st[jt][r] = e;
            rs += e;
        }
    }
    rs += __shfl_xor(rs, 16);
    rs += __shfl_xor(rs, 32);
    const float inv = 1.0f / (rs + 1e-8f);

    // ---- phase AGG^T: flash-chunked E through per-wave LDS strip ----
    ushort* myP = sPs + (wv << 4) * PS_S;
    f32x4 ag[4];
#pragma unroll
    for (int et = 0; et < 4; ++et) ag[et] = (f32x4){0.f, 0.f, 0.f, 0.f};
#pragma unroll
    for (int ks = 0; ks < 4; ++ks) {
#pragma unroll
        for (int h = 0; h < 2; ++h) {   // pack E cols 32ks..32ks+31 into chunk
            const int jt = (ks << 1) | h;
            uint p0 = pk_bf16(st[jt][0], st[jt][1]);
            uint p1 = pk_bf16(st[jt][2], st[jt][3]);
            *(uint2*)&myP[lr * PS_S + (h << 4) + (lg << 2)] = make_uint2(p0, p1);
        }
        bf16x8 pf = *(bf16x8*)&myP[lr * PS_S + (lg << 3)];
#pragma unroll
        for (int et = 0; et < 4; ++et) {
            bf16x8 ctf = *(bf16x8*)&sV[((et << 4) + lr) * CT_S + ((((ks << 2) | lg) ^ (et << 1)) << 3)];
            ag[et] = __builtin_amdgcn_mfma_f32_16x16x32_bf16(ctf, pf, ag[et], 0, 0, 0);
        }
    }
    // epilogue: normalize (deferred inv), .*C, relu  (lane holds AGG[irow][16et+4lg+r])
    float av[4][4];
#pragma unroll
    for (int et = 0; et < 4; ++et) {
        uint2 cb2 = *(const uint2*)&sCb[irow * CB_S + (et << 4) + (lg << 2)];
        float cv[4] = {bflo(cb2.x), bfhi(cb2.x), bflo(cb2.y), bfhi(cb2.y)};
#pragma unroll
        for (int r = 0; r < 4; ++r)
            av[et][r] = fmaxf(ag[et][r] * inv * cv[r], 0.f);
    }
    __syncthreads();                    // barrier 2: all Ct reads done -> sV becomes A2

    ushort* sA2 = sV;
#pragma unroll
    for (int et = 0; et < 4; ++et) {
        uint a0 = pk_bf16(av[et][0], av[et][1]);
        uint a1 = pk_bf16(av[et][2], av[et][3]);
        *(uint2*)&sA2[irow * A2_S + (et << 4) + (lg << 2)] = make_uint2(a0, a1);
    }

    // ---- phase OUT: relu([C, A2]) @ Wc  (Wt B-frags direct from L2) ----
    f32x4 oc[2];
    oc[0] = (f32x4){0.f, 0.f, 0.f, 0.f};
    oc[1] = (f32x4){0.f, 0.f, 0.f, 0.f};
#pragma unroll
    for (int ks = 0; ks < 4; ++ks) {
        bf16x8 afr;
        if (ks < 2) {
            afr = *(bf16x8*)&sCb[irow * CB_S + (ks << 5) + (lg << 3)];
#pragma unroll
            for (int q = 0; q < 8; ++q) afr[q] = afr[q] < (short)0 ? (short)0 : afr[q];  // bf16 relu
        } else {
            afr = *(bf16x8*)&sA2[irow * A2_S + ((ks - 2) << 5) + (lg << 3)];
        }
#pragma unroll
        for (int dt = 0; dt < 2; ++dt) {
            bf16x8 bfr = *(const bf16x8*)(wt + ((dt << 4) + lr) * 128 + (ks << 5) + (lg << 3));
            oc[dt] = __builtin_amdgcn_mfma_f32_16x16x32_bf16(afr, bfr, oc[dt], 0, 0, 0);
        }
    }
    float* op = out + bt * (NF * NCD);
#pragma unroll
    for (int dt = 0; dt < 2; ++dt)
#pragma unroll
        for (int r = 0; r < 4; ++r)
            op[(i0 + (lg << 2) + r) * NCD + (dt << 4) + lr] = oc[dt][r];
}

extern "C" void kernel_launch(void* const* d_in, const int* in_sizes, int n_in,
                              void* d_out, int out_size, void* d_ws, size_t ws_size,
                              hipStream_t stream) {
    const float* input_x       = (const float*)d_in[0];
    const int*   mask          = (const int*)d_in[1];
    const float* embed0        = (const float*)d_in[2];
    const float* embed1        = (const float*)d_in[3];
    const float* embed_missing = (const float*)d_in[4];
    const float* attn_w        = (const float*)d_in[5];
    const float* attn_b        = (const float*)d_in[6];
    const float* compress_w    = (const float*)d_in[7];
    float* out = (float*)d_out;

    char* ws = (char*)d_ws;
    uint*   mflag = (uint*)(ws + WS_MFLAG);
    ushort* dbp   = (ushort*)(ws + WS_DB);
    ushort* e1bp  = (ushort*)(ws + WS_E1B);
    ushort* embp  = (ushort*)(ws + WS_EMB);
    ushort* wbp   = (ushort*)(ws + WS_WB);
    ushort* wtp   = (ushort*)(ws + WS_WT);

    hipLaunchKernelGGL(prep_kernel, dim3(80), dim3(256), 0, stream,
                       mask, embed0, embed1, embed_missing, attn_w, compress_w,
                       mflag, dbp, e1bp, embp, wbp, wtp);
    hipLaunchKernelGGL(fused_kernel, dim3(NB * NT), dim3(512), 0, stream,
                       input_x, mflag, dbp, e1bp, embp, wbp, attn_b, wtp, out);
}